// Round 12
// baseline (251.561 us; speedup 1.0000x reference)
//
#include <hip/hip_runtime.h>
#include <hip/hip_bf16.h>

// CausalSelfAttention: B=4, T=2048, C=1024, H=16, HD=64
// Pipeline: x->bf16 | W->bf16^T | QKV GEMM (256^2 ring-4 counted-vmcnt) |
//           flash attn (r8 structure, 1024-block longest-first grid, 4 blocks/CU) |
//           proj GEMM

typedef __attribute__((ext_vector_type(8))) short bf16x8;
typedef __attribute__((ext_vector_type(4))) float f32x4;
typedef __attribute__((ext_vector_type(4))) int int4v;

#define B_ 4
#define T_ 2048
#define C_ 1024
#define H_ 16
#define HD_ 64
#define SCALE_LOG2E 0.18033688011112042f   // (1/8) * log2(e), folded into Q at GEMM epilogue

__device__ __forceinline__ unsigned short f2bf(float f) {
    union { __hip_bfloat16 b; unsigned short u; } c;
    c.b = __float2bfloat16(f);
    return c.u;
}

// ---------------- x f32 -> bf16 ----------------
__global__ __launch_bounds__(256) void k_conv(const float* __restrict__ in,
                                              unsigned short* __restrict__ out, int n) {
    int i = (blockIdx.x * 256 + threadIdx.x) * 4;
    if (i >= n) return;
    float4 v = *(const float4*)(in + i);
    unsigned short r[4] = { f2bf(v.x), f2bf(v.y), f2bf(v.z), f2bf(v.w) };
    *(unsigned long long*)(out + i) = *(const unsigned long long*)r;
}

// ---------------- W [R][Cin] f32 -> out [Cin][R] bf16 (transpose+convert) ----------------
__global__ __launch_bounds__(256) void k_transp(const float* __restrict__ in,
                                                unsigned short* __restrict__ out,
                                                int R, int Cin) {
    __shared__ float t[32][33];
    int bx = blockIdx.x, by = blockIdx.y;
    int j = threadIdx.x & 31, i0 = threadIdx.x >> 5;
#pragma unroll
    for (int k = 0; k < 4; k++) {
        int i = i0 + k * 8;
        t[i][j] = in[(size_t)(by * 32 + i) * Cin + bx * 32 + j];
    }
    __syncthreads();
#pragma unroll
    for (int k = 0; k < 4; k++) {
        int c = i0 + k * 8;
        out[(size_t)(bx * 32 + c) * R + by * 32 + j] = f2bf(t[j][c]);
    }
}

// ---------------- QKV GEMM: 256x256 tile, BK=32, ring-4 counted-vmcnt pipeline -------
#define QK_K 1024
#define QK_NT 32          // K tiles
__global__ __launch_bounds__(512, 2) void k_qkv(
    const unsigned short* __restrict__ A, const unsigned short* __restrict__ BT,
    const float* __restrict__ bias,
    unsigned short* __restrict__ Qb, unsigned short* __restrict__ Kb,
    unsigned short* __restrict__ Vt)
{
    __shared__ unsigned short lds[4][2][8192];   // [ring][A|B][256*32]

    const int tid = threadIdx.x;
    const int lane = tid & 63;
    const int w = tid >> 6;              // 0..7
    const int wm2 = w >> 2, wn4 = w & 3;
    const int l15 = lane & 15, lg = lane >> 4;

    // XCD-aware bijective swizzle: 384 blocks = 8 * 48
    const int orig = blockIdx.x;
    const int wg = (orig & 7) * 48 + (orig >> 3);
    const int bm = (wg / 12) * 256, bn = (wg % 12) * 256;

    const int srow = tid >> 2;           // + j*128
    const int scol = (tid & 3) << 3;     // k-offset in shorts

    f32x4 acc[8][4];
#pragma unroll
    for (int mf = 0; mf < 8; mf++)
#pragma unroll
        for (int nf = 0; nf < 4; nf++) acc[mf][nf] = (f32x4){0.f, 0.f, 0.f, 0.f};

    auto stage = [&](int Tt) {
        const int k0 = Tt << 5;
        const int rr = Tt & 3;
#pragma unroll
        for (int j = 0; j < 2; ++j) {
            __builtin_amdgcn_global_load_lds(
                (const __attribute__((address_space(1))) void*)
                    (A + (size_t)(bm + srow + j * 128) * QK_K + k0 + scol),
                (__attribute__((address_space(3))) void*)(&lds[rr][0][w * 512 + j * 4096]),
                16, 0, 0);
            __builtin_amdgcn_global_load_lds(
                (const __attribute__((address_space(1))) void*)
                    (BT + (size_t)(bn + srow + j * 128) * QK_K + k0 + scol),
                (__attribute__((address_space(3))) void*)(&lds[rr][1][w * 512 + j * 4096]),
                16, 0, 0);
        }
    };

    stage(0); stage(1); stage(2);        // 12 loads in flight

#pragma unroll 1
    for (int T = 0; T < QK_NT; ++T) {
        if (T <= QK_NT - 3)      { asm volatile("s_waitcnt vmcnt(8)" ::: "memory"); }
        else if (T == QK_NT - 2) { asm volatile("s_waitcnt vmcnt(4)" ::: "memory"); }
        else                     { asm volatile("s_waitcnt vmcnt(0)" ::: "memory"); }
        __builtin_amdgcn_s_barrier();    // publish tile T; reads of ring (T-1)&3 done
        if (T <= QK_NT - 4) stage(T + 3);

        const int rr = T & 3;
        const unsigned short* Ald = &lds[rr][0][0];
        const unsigned short* Bld = &lds[rr][1][0];
        bf16x8 af[8], bfr[4];
#pragma unroll
        for (int mf = 0; mf < 8; ++mf)
            af[mf] = *(const bf16x8*)(Ald + (wm2 * 128 + mf * 16 + l15) * 32 + lg * 8);
#pragma unroll
        for (int nf = 0; nf < 4; ++nf)
            bfr[nf] = *(const bf16x8*)(Bld + (wn4 * 64 + nf * 16 + l15) * 32 + lg * 8);

        __builtin_amdgcn_s_setprio(1);
#pragma unroll
        for (int mf = 0; mf < 8; ++mf)
#pragma unroll
            for (int nf = 0; nf < 4; ++nf)
                acc[mf][nf] = __builtin_amdgcn_mfma_f32_16x16x32_bf16(af[mf], bfr[nf], acc[mf][nf], 0, 0, 0);
        __builtin_amdgcn_s_setprio(0);
    }

    // epilogue: bias + scatter Q (pre-scaled) / K bf16 [B,H,T,64], V -> Vt [B,H,64,T]
#pragma unroll
    for (int mf = 0; mf < 8; ++mf) {
#pragma unroll
        for (int nf = 0; nf < 4; ++nf) {
            int col = bn + wn4 * 64 + nf * 16 + l15;
            float bval = bias[col];
            int row0 = bm + wm2 * 128 + mf * 16 + lg * 4;
            float vals[4];
#pragma unroll
            for (int r = 0; r < 4; r++) vals[r] = acc[mf][nf][r] + bval;
            int b = row0 >> 11, t0 = row0 & 2047;
            int which = col >> 10;
            int h = (col & 1023) >> 6, d = col & 63;
            if (which == 2) {
                unsigned short pk[4];
#pragma unroll
                for (int r = 0; r < 4; r++) pk[r] = f2bf(vals[r]);
                *(unsigned long long*)(&Vt[((size_t)(b * H_ + h) * HD_ + d) * T_ + t0]) =
                    *(const unsigned long long*)pk;
            } else {
                unsigned short* dst = which ? Kb : Qb;
                float sc_ = which ? 1.0f : SCALE_LOG2E;
#pragma unroll
                for (int r = 0; r < 4; r++)
                    dst[((size_t)(b * H_ + h) * T_ + t0 + r) * HD_ + d] = f2bf(vals[r] * sc_);
            }
        }
    }
}

// ---------------- proj GEMM: m97 structure, 128^2 tile ----------------
__global__ __launch_bounds__(256) void k_proj(
    const unsigned short* __restrict__ A, const unsigned short* __restrict__ BT,
    const float* __restrict__ bias, float* __restrict__ out, int M, int N, int K)
{
    __shared__ unsigned short As[128][32];
    __shared__ unsigned short Bs[128][32];
    const int tid = threadIdx.x;
    const int lane = tid & 63;
    const int wv = tid >> 6;
    const int wm = wv >> 1, wn = wv & 1;
    const int l15 = lane & 15, lg = lane >> 4;

    const int nwg = gridDim.x * gridDim.y;
    const int orig = blockIdx.y * gridDim.x + blockIdx.x;
    const int wg = (orig & 7) * (nwg >> 3) + (orig >> 3);
    const int bm = (wg / gridDim.x) * 128, bn = (wg % gridDim.x) * 128;

    f32x4 acc[4][4];
#pragma unroll
    for (int m = 0; m < 4; m++)
#pragma unroll
        for (int n = 0; n < 4; n++) acc[m][n] = (f32x4){0.f, 0.f, 0.f, 0.f};

    const int rl = lane >> 2;
    const int cl = (lane & 3) * 8;

    for (int k0 = 0; k0 < K; k0 += 32) {
#pragma unroll
        for (int i = 0; i < 2; i++) {
            int c = wv + i * 4;
            __builtin_amdgcn_global_load_lds(
                (const __attribute__((address_space(1))) void*)
                    (&A[(size_t)(bm + c * 16 + rl) * K + k0 + cl]),
                (__attribute__((address_space(3))) void*)(&As[c * 16][0]), 16, 0, 0);
            __builtin_amdgcn_global_load_lds(
                (const __attribute__((address_space(1))) void*)
                    (&BT[(size_t)(bn + c * 16 + rl) * K + k0 + cl]),
                (__attribute__((address_space(3))) void*)(&Bs[c * 16][0]), 16, 0, 0);
        }
        __syncthreads();
        bf16x8 af[4], bfr[4];
#pragma unroll
        for (int m = 0; m < 4; m++) af[m]  = *(const bf16x8*)(&As[wm * 64 + m * 16 + l15][lg * 8]);
#pragma unroll
        for (int n = 0; n < 4; n++) bfr[n] = *(const bf16x8*)(&Bs[wn * 64 + n * 16 + l15][lg * 8]);
        __builtin_amdgcn_s_setprio(1);
#pragma unroll
        for (int m = 0; m < 4; m++)
#pragma unroll
            for (int n = 0; n < 4; n++)
                acc[m][n] = __builtin_amdgcn_mfma_f32_16x16x32_bf16(af[m], bfr[n], acc[m][n], 0, 0, 0);
        __builtin_amdgcn_s_setprio(0);
        __syncthreads();
    }

#pragma unroll
    for (int m = 0; m < 4; m++) {
#pragma unroll
        for (int n = 0; n < 4; n++) {
            int col = bn + wn * 64 + n * 16 + l15;
            float bval = bias[col];
            int row0 = bm + wm * 64 + m * 16 + lg * 4;
#pragma unroll
            for (int r = 0; r < 4; r++) out[(size_t)(row0 + r) * N + col] = acc[m][n][r] + bval;
        }
    }
}

// ---------------- Flash attention (causal): 8-wave shared staging, 1 job/block -------
// Q,K: [B*H, T, 64] (Q pre-scaled).  Vt: [B*H, 64, T].
// 1024 blocks (16 q-tiles x 64 heads), longest-first: qt = 15-(j>>6), bh = j&63.
// 128 q-rows per block (16/wave x 8 waves). VGPR<=64 + LDS 32KB -> 4 blocks/CU
// resident (the r8 structure was grid-limited to 2/CU; this doubles wave TLP).
// S^T = mfma(K,Q): q-row = lane&15 lane-local. PV via k-slot permutation kappa;
// V staged column-permuted so vf is one contiguous ds_read_b128. K/V dbuf,
// XOR-swizzled, single barrier/tile, defer-max (T13).
__global__ __launch_bounds__(512, 8) void k_attn(
    const unsigned short* __restrict__ Qb, const unsigned short* __restrict__ Kb,
    const unsigned short* __restrict__ Vt, unsigned short* __restrict__ att)
{
    __shared__ unsigned short Ks[2][64][64];   // [buf][key][d], chunk16 ^= key&7
    __shared__ unsigned short Vs[2][64][64];   // [buf][d][newcol], chunk16 ^= d&7

    const int tid = threadIdx.x, lane = tid & 63, w = tid >> 6;   // w 0..7
    const int l15 = lane & 15, lg = lane >> 4;
    const int swq = l15 & 7;
    const int j = blockIdx.x;
    const int bh = j & 63;
    const int b = bh >> 4, h = bh & 15;
    const size_t kqbase = (size_t)bh * T_ * HD_;
    const size_t vtbase = (size_t)bh * HD_ * T_;

    const int r0 = tid >> 3;            // 0..63 staging row (one shot, 512 threads)
    const int mm = tid & 7;             // staging col chunk
    const int c8 = mm * 8;
    const int kch = mm;                               // K chunk (pre-swizzle)
    const int vch = 4 * (mm & 1) + (mm >> 2);         // V chunk half0 (pre-swizzle)
    const int voff = ((mm >> 1) & 1) * 4;             // shorts within chunk
    const int swr = r0 & 7;

    const int t = 15 - (j >> 6);            // longest-first 128-row q-tile
    const int qb = t * 128;
    const int qrow = qb + w * 16 + l15;     // this lane's q-row
    const int dtile = 2 * t + (w >> 2);     // wave-uniform diagonal tile
    const int ktlast = 2 * t + 1;           // block stages tiles 0..ktlast

    bf16x8 qf[2];
#pragma unroll
    for (int s = 0; s < 2; s++)
        qf[s] = *(const bf16x8*)(Qb + kqbase + (size_t)qrow * HD_ + s * 32 + lg * 8);

    f32x4 o[4];                   // o[cd][r] = O^T[d=cd*16+lg*4+r][q=l15]
    float m_run = -1e30f, l_run = 0.f;
#pragma unroll
    for (int c = 0; c < 4; c++) o[c] = (f32x4){0.f, 0.f, 0.f, 0.f};

    // prefetch tile 0
    int4v kreg, vreg;
    kreg = *(const int4v*)(Kb + kqbase + (size_t)r0 * HD_ + c8);
    vreg = *(const int4v*)(Vt + vtbase + (size_t)r0 * T_ + c8);

#pragma unroll 1
    for (int kt = 0; kt <= ktlast; ++kt) {
        const int bufi = kt & 1;
        *(int4v*)(&Ks[bufi][r0][(kch ^ swr) * 8]) = kreg;
        {
            unsigned long long vlo = ((const unsigned long long*)&vreg)[0];
            unsigned long long vhi = ((const unsigned long long*)&vreg)[1];
            *(unsigned long long*)(&Vs[bufi][r0][((vch       ^ swr) * 8) + voff]) = vlo;
            *(unsigned long long*)(&Vs[bufi][r0][(((vch + 2) ^ swr) * 8) + voff]) = vhi;
        }
        if (kt < ktlast) {                  // issue next tile's loads early (T14)
            int nk = (kt + 1) * 64;
            kreg = *(const int4v*)(Kb + kqbase + (size_t)(nk + r0) * HD_ + c8);
            vreg = *(const int4v*)(Vt + vtbase + (size_t)r0 * T_ + nk + c8);
        }
        __syncthreads();                    // single barrier per tile

        if (kt <= dtile) {
            // S^T = K Q^T : sv[c][r] = S[key=kt*64+c*16+lg*4+r][q=l15]
            float sv[4][4];
            const bool diag = (kt == dtile);
            __builtin_amdgcn_s_setprio(1);
#pragma unroll
            for (int c = 0; c < 4; c++) {
                bf16x8 kf0 = *(const bf16x8*)(&Ks[bufi][c * 16 + l15][(lg       ^ swq) * 8]);
                bf16x8 kf1 = *(const bf16x8*)(&Ks[bufi][c * 16 + l15][((4 + lg) ^ swq) * 8]);
                f32x4 s4 = (f32x4){0.f, 0.f, 0.f, 0.f};
                s4 = __builtin_amdgcn_mfma_f32_16x16x32_bf16(kf0, qf[0], s4, 0, 0, 0);
                s4 = __builtin_amdgcn_mfma_f32_16x16x32_bf16(kf1, qf[1], s4, 0, 0, 0);
                if (diag) {
                    int key0 = kt * 64 + c * 16 + lg * 4;
#pragma unroll
                    for (int r = 0; r < 4; r++)
                        sv[c][r] = (key0 + r > qrow) ? -1e30f : s4[r];
                } else {
#pragma unroll
                    for (int r = 0; r < 4; r++) sv[c][r] = s4[r];
                }
            }
            __builtin_amdgcn_s_setprio(0);

            // row max (whole q-row lane-local across 4 lane-group copies)
            float tm = fmaxf(fmaxf(fmaxf(sv[0][0], sv[0][1]), fmaxf(sv[0][2], sv[0][3])),
                             fmaxf(fmaxf(sv[1][0], sv[1][1]), fmaxf(sv[1][2], sv[1][3])));
            tm = fmaxf(tm, fmaxf(fmaxf(fmaxf(sv[2][0], sv[2][1]), fmaxf(sv[2][2], sv[2][3])),
                                 fmaxf(fmaxf(sv[3][0], sv[3][1]), fmaxf(sv[3][2], sv[3][3]))));
            tm = fmaxf(tm, __shfl_xor(tm, 16));
            tm = fmaxf(tm, __shfl_xor(tm, 32));

            // defer-max (T13): rescale only when a row's max grew past THR=8
            if (__any(tm - m_run > 8.f)) {
                float mn = fmaxf(m_run, tm);
                float alpha = exp2f(m_run - mn);
                m_run = mn;
                l_run *= alpha;
#pragma unroll
                for (int cd = 0; cd < 4; cd++)
#pragma unroll
                    for (int r = 0; r < 4; r++) o[cd][r] *= alpha;
            }

            // P in registers, packed per the kappa slot order (no LDS, no shuffles)
            float ps = 0.f;
            bf16x8 pf0, pf1;
#pragma unroll
            for (int c = 0; c < 2; c++)
#pragma unroll
                for (int r = 0; r < 4; r++) {
                    float pv0 = exp2f(sv[c][r] - m_run);
                    float pv1 = exp2f(sv[c + 2][r] - m_run);
                    ps += pv0 + pv1;
                    pf0[c * 4 + r] = (short)f2bf(pv0);
                    pf1[c * 4 + r] = (short)f2bf(pv1);
                }
            l_run += ps;

            // O^T += V~ P~ with matching slot->key map on both operands
            __builtin_amdgcn_s_setprio(1);
#pragma unroll
            for (int cd = 0; cd < 4; cd++) {
                bf16x8 vf0 = *(const bf16x8*)(&Vs[bufi][cd * 16 + l15][((2 * lg)     ^ swq) * 8]);
                bf16x8 vf1 = *(const bf16x8*)(&Vs[bufi][cd * 16 + l15][((2 * lg + 1) ^ swq) * 8]);
                o[cd] = __builtin_amdgcn_mfma_f32_16x16x32_bf16(vf0, pf0, o[cd], 0, 0, 0);
                o[cd] = __builtin_amdgcn_mfma_f32_16x16x32_bf16(vf1, pf1, o[cd], 0, 0, 0);
            }
            __builtin_amdgcn_s_setprio(0);
        }
    }

    // epilogue: cross-lane l reduce, normalize, store packed
    float ls = l_run;
    ls += __shfl_xor(ls, 16);
    ls += __shfl_xor(ls, 32);
    float inv = 1.0f / ls;
    const size_t rowbase = ((size_t)(b * T_ + qrow)) * C_ + h * 64;
#pragma unroll
    for (int cd = 0; cd < 4; cd++) {
        unsigned short ok[4];
#pragma unroll
        for (int r = 0; r < 4; r++) ok[r] = f2bf(o[cd][r] * inv);
        *(unsigned long long*)(&att[rowbase + cd * 16 + lg * 4]) =
            *(const unsigned long long*)ok;
    }
}

extern "C" void kernel_launch(void* const* d_in, const int* in_sizes, int n_in,
                              void* d_out, int out_size, void* d_ws, size_t ws_size,
                              hipStream_t stream)
{
    const float* x      = (const float*)d_in[0];
    const float* W_qkv  = (const float*)d_in[1];
    const float* b_qkv  = (const float*)d_in[2];
    const float* W_proj = (const float*)d_in[3];
    const float* b_proj = (const float*)d_in[4];
    float* out = (float*)d_out;

    char* p = (char*)d_ws;
    unsigned short* xbf    = (unsigned short*)p; p += (size_t)8192 * 1024 * 2;  // reused as att out
    unsigned short* wqkvT  = (unsigned short*)p; p += (size_t)3072 * 1024 * 2;
    unsigned short* wprojT = (unsigned short*)p; p += (size_t)1024 * 1024 * 2;
    unsigned short* Qb     = (unsigned short*)p; p += (size_t)8192 * 1024 * 2;
    unsigned short* Kb     = (unsigned short*)p; p += (size_t)8192 * 1024 * 2;
    unsigned short* Vt     = (unsigned short*)p; p += (size_t)8192 * 1024 * 2;  // [B*H, 64, T]

    k_conv<<<8192, 256, 0, stream>>>(x, xbf, 8192 * 1024);
    k_transp<<<dim3(96, 32), 256, 0, stream>>>(W_qkv, wqkvT, 1024, 3072);
    k_transp<<<dim3(32, 32), 256, 0, stream>>>(W_proj, wprojT, 1024, 1024);
    k_qkv<<<384, 512, 0, stream>>>(xbf, wqkvT, b_qkv, Qb, Kb, Vt);
    k_attn<<<1024, 512, 0, stream>>>(Qb, Kb, Vt, xbf);
    k_proj<<<dim3(8, 64), 256, 0, stream>>>(xbf, wprojT, b_proj, out, 8192, 1024, 1024);
}

// Round 13
// 202.853 us; speedup vs baseline: 1.2401x; 1.2401x over previous
//
#include <hip/hip_runtime.h>
#include <hip/hip_bf16.h>

// CausalSelfAttention: B=4, T=2048, C=1024, H=16, HD=64
// Pipeline: x->bf16 | W->bf16^T | QKV GEMM (128x256 tile, ring-4 counted-vmcnt,
//           768 blocks = 3.0 exact CU rounds) | flash attn (r10 measured-best) | proj GEMM

typedef __attribute__((ext_vector_type(8))) short bf16x8;
typedef __attribute__((ext_vector_type(4))) float f32x4;
typedef __attribute__((ext_vector_type(4))) int int4v;

#define B_ 4
#define T_ 2048
#define C_ 1024
#define H_ 16
#define HD_ 64
#define SCALE_LOG2E 0.18033688011112042f   // (1/8) * log2(e), folded into Q at GEMM epilogue

__device__ __forceinline__ unsigned short f2bf(float f) {
    union { __hip_bfloat16 b; unsigned short u; } c;
    c.b = __float2bfloat16(f);
    return c.u;
}

// ---------------- x f32 -> bf16 ----------------
__global__ __launch_bounds__(256) void k_conv(const float* __restrict__ in,
                                              unsigned short* __restrict__ out, int n) {
    int i = (blockIdx.x * 256 + threadIdx.x) * 4;
    if (i >= n) return;
    float4 v = *(const float4*)(in + i);
    unsigned short r[4] = { f2bf(v.x), f2bf(v.y), f2bf(v.z), f2bf(v.w) };
    *(unsigned long long*)(out + i) = *(const unsigned long long*)r;
}

// ---------------- W [R][Cin] f32 -> out [Cin][R] bf16 (transpose+convert) ----------------
__global__ __launch_bounds__(256) void k_transp(const float* __restrict__ in,
                                                unsigned short* __restrict__ out,
                                                int R, int Cin) {
    __shared__ float t[32][33];
    int bx = blockIdx.x, by = blockIdx.y;
    int j = threadIdx.x & 31, i0 = threadIdx.x >> 5;
#pragma unroll
    for (int k = 0; k < 4; k++) {
        int i = i0 + k * 8;
        t[i][j] = in[(size_t)(by * 32 + i) * Cin + bx * 32 + j];
    }
    __syncthreads();
#pragma unroll
    for (int k = 0; k < 4; k++) {
        int c = i0 + k * 8;
        out[(size_t)(bx * 32 + c) * R + by * 32 + j] = f2bf(t[j][c]);
    }
}

// ---------------- QKV GEMM: 128x256 tile, BK=32, ring-4 counted-vmcnt pipeline -------
// A = xbf [8192][1024], BT = wqkvT [3072][1024]. 512 threads = 8 waves (2M x 4N),
// per-wave 64x64 output (4x4 frags), 16 MFMA + 8 ds_read_b128 per K-tile.
// Ring of 4 K-tile buffers (A 8KB + B 16KB each = 96KB LDS), prefetch distance 3.
// 768 blocks = 3.0 exact rounds on 256 CUs (fixes the 384-block 1.5-round tax).
// Per-thread 3 loads/tile -> ledger: vmcnt(6) steady, (3) and (0) at drain.
#define QK_K 1024
#define QK_NT 32          // K tiles
__global__ __launch_bounds__(512, 2) void k_qkv(
    const unsigned short* __restrict__ A, const unsigned short* __restrict__ BT,
    const float* __restrict__ bias,
    unsigned short* __restrict__ Qb, unsigned short* __restrict__ Kb,
    unsigned short* __restrict__ Vt)
{
    __shared__ unsigned short lds[4][12288];   // [ring][A(128x32) | B(256x32)]

    const int tid = threadIdx.x;
    const int lane = tid & 63;
    const int w = tid >> 6;              // 0..7
    const int wm2 = w >> 2, wn4 = w & 3;
    const int l15 = lane & 15, lg = lane >> 4;

    // XCD-aware bijective swizzle: 768 blocks = 8 * 96
    const int orig = blockIdx.x;
    const int wg = (orig & 7) * 96 + (orig >> 3);
    const int bm = (wg / 12) * 128, bn = (wg % 12) * 256;

    f32x4 acc[4][4];
#pragma unroll
    for (int mf = 0; mf < 4; mf++)
#pragma unroll
        for (int nf = 0; nf < 4; nf++) acc[mf][nf] = (f32x4){0.f, 0.f, 0.f, 0.f};

    const int srow = tid >> 2;           // 0..127
    const int scol = (tid & 3) << 3;     // k-offset in shorts

    auto stage = [&](int Tt) {
        const int k0 = Tt << 5;
        const int rr = Tt & 3;
        // A tile: 128x32, one 16B load/thread; dest linear = tid*8
        __builtin_amdgcn_global_load_lds(
            (const __attribute__((address_space(1))) void*)
                (A + (size_t)(bm + srow) * QK_K + k0 + scol),
            (__attribute__((address_space(3))) void*)(&lds[rr][w * 512]), 16, 0, 0);
        // B tile: 256x32, two 16B loads/thread; dest = 4096 + tid*8 + j*4096
#pragma unroll
        for (int j = 0; j < 2; ++j) {
            __builtin_amdgcn_global_load_lds(
                (const __attribute__((address_space(1))) void*)
                    (BT + (size_t)(bn + srow + j * 128) * QK_K + k0 + scol),
                (__attribute__((address_space(3))) void*)(&lds[rr][4096 + w * 512 + j * 4096]),
                16, 0, 0);
        }
    };

    stage(0); stage(1); stage(2);        // 9 loads/thread in flight

#pragma unroll 1
    for (int T = 0; T < QK_NT; ++T) {
        if (T <= QK_NT - 3)      { asm volatile("s_waitcnt vmcnt(6)" ::: "memory"); }
        else if (T == QK_NT - 2) { asm volatile("s_waitcnt vmcnt(3)" ::: "memory"); }
        else                     { asm volatile("s_waitcnt vmcnt(0)" ::: "memory"); }
        __builtin_amdgcn_s_barrier();    // publish tile T; reads of ring (T-1)&3 done
        if (T <= QK_NT - 4) stage(T + 3);

        const int rr = T & 3;
        const unsigned short* Ald = &lds[rr][0];
        const unsigned short* Bld = &lds[rr][4096];
        bf16x8 af[4], bfr[4];
#pragma unroll
        for (int mf = 0; mf < 4; ++mf)
            af[mf] = *(const bf16x8*)(Ald + (wm2 * 64 + mf * 16 + l15) * 32 + lg * 8);
#pragma unroll
        for (int nf = 0; nf < 4; ++nf)
            bfr[nf] = *(const bf16x8*)(Bld + (wn4 * 64 + nf * 16 + l15) * 32 + lg * 8);

        __builtin_amdgcn_s_setprio(1);
#pragma unroll
        for (int mf = 0; mf < 4; ++mf)
#pragma unroll
            for (int nf = 0; nf < 4; ++nf)
                acc[mf][nf] = __builtin_amdgcn_mfma_f32_16x16x32_bf16(af[mf], bfr[nf], acc[mf][nf], 0, 0, 0);
        __builtin_amdgcn_s_setprio(0);
    }

    // epilogue: bias + scatter Q (pre-scaled) / K bf16 [B,H,T,64], V -> Vt [B,H,64,T]
#pragma unroll
    for (int mf = 0; mf < 4; ++mf) {
#pragma unroll
        for (int nf = 0; nf < 4; ++nf) {
            int col = bn + wn4 * 64 + nf * 16 + l15;
            float bval = bias[col];
            int row0 = bm + wm2 * 64 + mf * 16 + lg * 4;
            float vals[4];
#pragma unroll
            for (int r = 0; r < 4; r++) vals[r] = acc[mf][nf][r] + bval;
            int b = row0 >> 11, t0 = row0 & 2047;
            int which = col >> 10;
            int h = (col & 1023) >> 6, d = col & 63;
            if (which == 2) {
                unsigned short pk[4];
#pragma unroll
                for (int r = 0; r < 4; r++) pk[r] = f2bf(vals[r]);
                *(unsigned long long*)(&Vt[((size_t)(b * H_ + h) * HD_ + d) * T_ + t0]) =
                    *(const unsigned long long*)pk;
            } else {
                unsigned short* dst = which ? Kb : Qb;
                float sc_ = which ? 1.0f : SCALE_LOG2E;
#pragma unroll
                for (int r = 0; r < 4; r++)
                    dst[((size_t)(b * H_ + h) * T_ + t0 + r) * HD_ + d] = f2bf(vals[r] * sc_);
            }
        }
    }
}

// ---------------- proj GEMM: m97 structure, 128^2 tile ----------------
__global__ __launch_bounds__(256) void k_proj(
    const unsigned short* __restrict__ A, const unsigned short* __restrict__ BT,
    const float* __restrict__ bias, float* __restrict__ out, int M, int N, int K)
{
    __shared__ unsigned short As[128][32];
    __shared__ unsigned short Bs[128][32];
    const int tid = threadIdx.x;
    const int lane = tid & 63;
    const int wv = tid >> 6;
    const int wm = wv >> 1, wn = wv & 1;
    const int l15 = lane & 15, lg = lane >> 4;

    const int nwg = gridDim.x * gridDim.y;
    const int orig = blockIdx.y * gridDim.x + blockIdx.x;
    const int wg = (orig & 7) * (nwg >> 3) + (orig >> 3);
    const int bm = (wg / gridDim.x) * 128, bn = (wg % gridDim.x) * 128;

    f32x4 acc[4][4];
#pragma unroll
    for (int m = 0; m < 4; m++)
#pragma unroll
        for (int n = 0; n < 4; n++) acc[m][n] = (f32x4){0.f, 0.f, 0.f, 0.f};

    const int rl = lane >> 2;
    const int cl = (lane & 3) * 8;

    for (int k0 = 0; k0 < K; k0 += 32) {
#pragma unroll
        for (int i = 0; i < 2; i++) {
            int c = wv + i * 4;
            __builtin_amdgcn_global_load_lds(
                (const __attribute__((address_space(1))) void*)
                    (&A[(size_t)(bm + c * 16 + rl) * K + k0 + cl]),
                (__attribute__((address_space(3))) void*)(&As[c * 16][0]), 16, 0, 0);
            __builtin_amdgcn_global_load_lds(
                (const __attribute__((address_space(1))) void*)
                    (&BT[(size_t)(bn + c * 16 + rl) * K + k0 + cl]),
                (__attribute__((address_space(3))) void*)(&Bs[c * 16][0]), 16, 0, 0);
        }
        __syncthreads();
        bf16x8 af[4], bfr[4];
#pragma unroll
        for (int m = 0; m < 4; m++) af[m]  = *(const bf16x8*)(&As[wm * 64 + m * 16 + l15][lg * 8]);
#pragma unroll
        for (int n = 0; n < 4; n++) bfr[n] = *(const bf16x8*)(&Bs[wn * 64 + n * 16 + l15][lg * 8]);
        __builtin_amdgcn_s_setprio(1);
#pragma unroll
        for (int m = 0; m < 4; m++)
#pragma unroll
            for (int n = 0; n < 4; n++)
                acc[m][n] = __builtin_amdgcn_mfma_f32_16x16x32_bf16(af[m], bfr[n], acc[m][n], 0, 0, 0);
        __builtin_amdgcn_s_setprio(0);
        __syncthreads();
    }

#pragma unroll
    for (int m = 0; m < 4; m++) {
#pragma unroll
        for (int n = 0; n < 4; n++) {
            int col = bn + wn * 64 + n * 16 + l15;
            float bval = bias[col];
            int row0 = bm + wm * 64 + m * 16 + lg * 4;
#pragma unroll
            for (int r = 0; r < 4; r++) out[(size_t)(row0 + r) * N + col] = acc[m][n][r] + bval;
        }
    }
}

// ---------------- Flash attention (causal): r10 measured-best (82.1 us) ----------------
// 128 q-rows per job (16/wave x 8 waves); block runs pair (15-bx, bx): uniform 36
// staged tiles/block. S^T = mfma(K,Q); PV via kappa slot permutation; K/V dbuf,
// XOR-swizzled, 1 barrier/tile; defer-max. launch_bounds (512,4): VGPR 48, no spills.
__global__ __launch_bounds__(512, 4) void k_attn(
    const unsigned short* __restrict__ Qb, const unsigned short* __restrict__ Kb,
    const unsigned short* __restrict__ Vt, unsigned short* __restrict__ att)
{
    __shared__ unsigned short Ks[2][64][64];   // [buf][key][d], chunk16 ^= key&7
    __shared__ unsigned short Vs[2][64][64];   // [buf][d][newcol], chunk16 ^= d&7

    const int tid = threadIdx.x, lane = tid & 63, w = tid >> 6;   // w 0..7
    const int l15 = lane & 15, lg = lane >> 4;
    const int swq = l15 & 7;
    const int bh = blockIdx.y;
    const int b = bh >> 4, h = bh & 15;
    const size_t kqbase = (size_t)bh * T_ * HD_;
    const size_t vtbase = (size_t)bh * HD_ * T_;

    const int r0 = tid >> 3;            // 0..63 staging row (one shot, 512 threads)
    const int mm = tid & 7;             // staging col chunk
    const int c8 = mm * 8;
    const int kch = mm;                               // K chunk (pre-swizzle)
    const int vch = 4 * (mm & 1) + (mm >> 2);         // V chunk half0 (pre-swizzle)
    const int voff = ((mm >> 1) & 1) * 4;             // shorts within chunk
    const int swr = r0 & 7;

#pragma unroll 1
    for (int job = 0; job < 2; ++job) {
        const int t = job ? (int)blockIdx.x : 15 - (int)blockIdx.x;  // 128-row q-tile
        const int qb = t * 128;
        const int qrow = qb + w * 16 + l15;     // this lane's q-row
        const int dtile = 2 * t + (w >> 2);     // wave-uniform diagonal tile
        const int ktlast = 2 * t + 1;           // block stages tiles 0..ktlast

        bf16x8 qf[2];
#pragma unroll
        for (int s = 0; s < 2; s++)
            qf[s] = *(const bf16x8*)(Qb + kqbase + (size_t)qrow * HD_ + s * 32 + lg * 8);

        f32x4 o[4];                   // o[cd][r] = O^T[d=cd*16+lg*4+r][q=l15]
        float m_run = -1e30f, l_run = 0.f;
#pragma unroll
        for (int c = 0; c < 4; c++) o[c] = (f32x4){0.f, 0.f, 0.f, 0.f};

        // prefetch tile 0
        int4v kreg, vreg;
        kreg = *(const int4v*)(Kb + kqbase + (size_t)r0 * HD_ + c8);
        vreg = *(const int4v*)(Vt + vtbase + (size_t)r0 * T_ + c8);

        for (int kt = 0; kt <= ktlast; ++kt) {
            const int bufi = kt & 1;
            *(int4v*)(&Ks[bufi][r0][(kch ^ swr) * 8]) = kreg;
            {
                unsigned long long vlo = ((const unsigned long long*)&vreg)[0];
                unsigned long long vhi = ((const unsigned long long*)&vreg)[1];
                *(unsigned long long*)(&Vs[bufi][r0][((vch       ^ swr) * 8) + voff]) = vlo;
                *(unsigned long long*)(&Vs[bufi][r0][(((vch + 2) ^ swr) * 8) + voff]) = vhi;
            }
            if (kt < ktlast) {                  // issue next tile's loads early (T14)
                int nk = (kt + 1) * 64;
                kreg = *(const int4v*)(Kb + kqbase + (size_t)(nk + r0) * HD_ + c8);
                vreg = *(const int4v*)(Vt + vtbase + (size_t)r0 * T_ + nk + c8);
            }
            __syncthreads();                    // single barrier per tile

            if (kt <= dtile) {
                // S^T = K Q^T : sv[c][r] = S[key=kt*64+c*16+lg*4+r][q=l15]
                float sv[4][4];
                const bool diag = (kt == dtile);
                __builtin_amdgcn_s_setprio(1);
#pragma unroll
                for (int c = 0; c < 4; c++) {
                    bf16x8 kf0 = *(const bf16x8*)(&Ks[bufi][c * 16 + l15][(lg       ^ swq) * 8]);
                    bf16x8 kf1 = *(const bf16x8*)(&Ks[bufi][c * 16 + l15][((4 + lg) ^ swq) * 8]);
                    f32x4 s4 = (f32x4){0.f, 0.f, 0.f, 0.f};
                    s4 = __builtin_amdgcn_mfma_f32_16x16x32_bf16(kf0, qf[0], s4, 0, 0, 0);
                    s4 = __builtin_amdgcn_mfma_f32_16x16x32_bf16(kf1, qf[1], s4, 0, 0, 0);
                    if (diag) {
                        int key0 = kt * 64 + c * 16 + lg * 4;
#pragma unroll
                        for (int r = 0; r < 4; r++)
                            sv[c][r] = (key0 + r > qrow) ? -1e30f : s4[r];
                    } else {
#pragma unroll
                        for (int r = 0; r < 4; r++) sv[c][r] = s4[r];
                    }
                }
                __builtin_amdgcn_s_setprio(0);

                // row max (whole q-row lane-local across 4 lane-group copies)
                float tm = fmaxf(fmaxf(fmaxf(sv[0][0], sv[0][1]), fmaxf(sv[0][2], sv[0][3])),
                                 fmaxf(fmaxf(sv[1][0], sv[1][1]), fmaxf(sv[1][2], sv[1][3])));
                tm = fmaxf(tm, fmaxf(fmaxf(fmaxf(sv[2][0], sv[2][1]), fmaxf(sv[2][2], sv[2][3])),
                                     fmaxf(fmaxf(sv[3][0], sv[3][1]), fmaxf(sv[3][2], sv[3][3]))));
                tm = fmaxf(tm, __shfl_xor(tm, 16));
                tm = fmaxf(tm, __shfl_xor(tm, 32));

                // defer-max (T13): rescale only when a row's max grew past THR=8
                if (__any(tm - m_run > 8.f)) {
                    float mn = fmaxf(m_run, tm);
                    float alpha = exp2f(m_run - mn);
                    m_run = mn;
                    l_run *= alpha;
#pragma unroll
                    for (int cd = 0; cd < 4; cd++)
#pragma unroll
                        for (int r = 0; r < 4; r++) o[cd][r] *= alpha;
                }

                // P in registers, packed per the kappa slot order (no LDS, no shuffles)
                float ps = 0.f;
                bf16x8 pf0, pf1;
#pragma unroll
                for (int c = 0; c < 2; c++)
#pragma unroll
                    for (int r = 0; r < 4; r++) {
                        float pv0 = exp2f(sv[c][r] - m_run);
                        float pv1 = exp2f(sv[c + 2][r] - m_run);
                        ps += pv0 + pv1;
                        pf0[c * 4 + r] = (short)f2bf(pv0);
                        pf1[c * 4 + r] = (short)f2bf(pv1);
                    }
                l_run += ps;

                // O^T += V~ P~ with matching slot->key map on both operands
                __builtin_amdgcn_s_setprio(1);
#pragma unroll
                for (int cd = 0; cd < 4; cd++) {
                    bf16x8 vf0 = *(const bf16x8*)(&Vs[bufi][cd * 16 + l15][((2 * lg)     ^ swq) * 8]);
                    bf16x8 vf1 = *(const bf16x8*)(&Vs[bufi][cd * 16 + l15][((2 * lg + 1) ^ swq) * 8]);
                    o[cd] = __builtin_amdgcn_mfma_f32_16x16x32_bf16(vf0, pf0, o[cd], 0, 0, 0);
                    o[cd] = __builtin_amdgcn_mfma_f32_16x16x32_bf16(vf1, pf1, o[cd], 0, 0, 0);
                }
                __builtin_amdgcn_s_setprio(0);
            }
        }
        __syncthreads();                        // protect LDS before next job's staging

        // epilogue: cross-lane l reduce, normalize, store packed
        float ls = l_run;
        ls += __shfl_xor(ls, 16);
        ls += __shfl_xor(ls, 32);
        float inv = 1.0f / ls;
        const size_t rowbase = ((size_t)(b * T_ + qrow)) * C_ + h * 64;
#pragma unroll
        for (int cd = 0; cd < 4; cd++) {
            unsigned short ok[4];
#pragma unroll
            for (int r = 0; r < 4; r++) ok[r] = f2bf(o[cd][r] * inv);
            *(unsigned long long*)(&att[rowbase + cd * 16 + lg * 4]) =
                *(const unsigned long long*)ok;
        }
    }
}

extern "C" void kernel_launch(void* const* d_in, const int* in_sizes, int n_in,
                              void* d_out, int out_size, void* d_ws, size_t ws_size,
                              hipStream_t stream)
{
    const float* x      = (const float*)d_in[0];
    const float* W_qkv  = (const float*)d_in[1];
    const float* b_qkv  = (const float*)d_in[2];
    const float* W_proj = (const float*)d_in[3];
    const float* b_proj = (const float*)d_in[4];
    float* out = (float*)d_out;

    char* p = (char*)d_ws;
    unsigned short* xbf    = (unsigned short*)p; p += (size_t)8192 * 1024 * 2;  // reused as att out
    unsigned short* wqkvT  = (unsigned short*)p; p += (size_t)3072 * 1024 * 2;
    unsigned short* wprojT = (unsigned short*)p; p += (size_t)1024 * 1024 * 2;
    unsigned short* Qb     = (unsigned short*)p; p += (size_t)8192 * 1024 * 2;
    unsigned short* Kb     = (unsigned short*)p; p += (size_t)8192 * 1024 * 2;
    unsigned short* Vt     = (unsigned short*)p; p += (size_t)8192 * 1024 * 2;  // [B*H, 64, T]

    k_conv<<<8192, 256, 0, stream>>>(x, xbf, 8192 * 1024);
    k_transp<<<dim3(96, 32), 256, 0, stream>>>(W_qkv, wqkvT, 1024, 3072);
    k_transp<<<dim3(32, 32), 256, 0, stream>>>(W_proj, wprojT, 1024, 1024);
    k_qkv<<<768, 512, 0, stream>>>(xbf, wqkvT, b_qkv, Qb, Kb, Vt);
    k_attn<<<dim3(8, 64), 512, 0, stream>>>(Qb, Kb, Vt, xbf);
    k_proj<<<dim3(8, 64), 256, 0, stream>>>(xbf, wprojT, b_proj, out, 8192, 1024, 1024);
}

// Round 14
// 190.157 us; speedup vs baseline: 1.3229x; 1.0668x over previous
//
#include <hip/hip_runtime.h>
#include <hip/hip_bf16.h>

// CausalSelfAttention: B=4, T=2048, C=1024, H=16, HD=64
// Pipeline: x->bf16 | W->bf16^T | QKV GEMM (256^2 ring-4 counted-vmcnt, r10) |
//           flash attn (r10 inner loop, 1024-block longest-first grid, 4 blocks/CU,
//           launch_bounds(512,4) -- r12's spill bug fixed) | proj GEMM

typedef __attribute__((ext_vector_type(8))) short bf16x8;
typedef __attribute__((ext_vector_type(4))) float f32x4;
typedef __attribute__((ext_vector_type(4))) int int4v;

#define B_ 4
#define T_ 2048
#define C_ 1024
#define H_ 16
#define HD_ 64
#define SCALE_LOG2E 0.18033688011112042f   // (1/8) * log2(e), folded into Q at GEMM epilogue

__device__ __forceinline__ unsigned short f2bf(float f) {
    union { __hip_bfloat16 b; unsigned short u; } c;
    c.b = __float2bfloat16(f);
    return c.u;
}

// ---------------- x f32 -> bf16 ----------------
__global__ __launch_bounds__(256) void k_conv(const float* __restrict__ in,
                                              unsigned short* __restrict__ out, int n) {
    int i = (blockIdx.x * 256 + threadIdx.x) * 4;
    if (i >= n) return;
    float4 v = *(const float4*)(in + i);
    unsigned short r[4] = { f2bf(v.x), f2bf(v.y), f2bf(v.z), f2bf(v.w) };
    *(unsigned long long*)(out + i) = *(const unsigned long long*)r;
}

// ---------------- W [R][Cin] f32 -> out [Cin][R] bf16 (transpose+convert) ----------------
__global__ __launch_bounds__(256) void k_transp(const float* __restrict__ in,
                                                unsigned short* __restrict__ out,
                                                int R, int Cin) {
    __shared__ float t[32][33];
    int bx = blockIdx.x, by = blockIdx.y;
    int j = threadIdx.x & 31, i0 = threadIdx.x >> 5;
#pragma unroll
    for (int k = 0; k < 4; k++) {
        int i = i0 + k * 8;
        t[i][j] = in[(size_t)(by * 32 + i) * Cin + bx * 32 + j];
    }
    __syncthreads();
#pragma unroll
    for (int k = 0; k < 4; k++) {
        int c = i0 + k * 8;
        out[(size_t)(bx * 32 + c) * R + by * 32 + j] = f2bf(t[j][c]);
    }
}

// ---------------- QKV GEMM: 256x256 tile, BK=32, ring-4 counted-vmcnt (r10) ----------
#define QK_K 1024
#define QK_NT 32          // K tiles
__global__ __launch_bounds__(512, 2) void k_qkv(
    const unsigned short* __restrict__ A, const unsigned short* __restrict__ BT,
    const float* __restrict__ bias,
    unsigned short* __restrict__ Qb, unsigned short* __restrict__ Kb,
    unsigned short* __restrict__ Vt)
{
    __shared__ unsigned short lds[4][2][8192];   // [ring][A|B][256*32]

    const int tid = threadIdx.x;
    const int lane = tid & 63;
    const int w = tid >> 6;              // 0..7
    const int wm2 = w >> 2, wn4 = w & 3;
    const int l15 = lane & 15, lg = lane >> 4;

    // XCD-aware bijective swizzle: 384 blocks = 8 * 48
    const int orig = blockIdx.x;
    const int wg = (orig & 7) * 48 + (orig >> 3);
    const int bm = (wg / 12) * 256, bn = (wg % 12) * 256;

    const int srow = tid >> 2;           // + j*128
    const int scol = (tid & 3) << 3;     // k-offset in shorts

    f32x4 acc[8][4];
#pragma unroll
    for (int mf = 0; mf < 8; mf++)
#pragma unroll
        for (int nf = 0; nf < 4; nf++) acc[mf][nf] = (f32x4){0.f, 0.f, 0.f, 0.f};

    auto stage = [&](int Tt) {
        const int k0 = Tt << 5;
        const int rr = Tt & 3;
#pragma unroll
        for (int j = 0; j < 2; ++j) {
            __builtin_amdgcn_global_load_lds(
                (const __attribute__((address_space(1))) void*)
                    (A + (size_t)(bm + srow + j * 128) * QK_K + k0 + scol),
                (__attribute__((address_space(3))) void*)(&lds[rr][0][w * 512 + j * 4096]),
                16, 0, 0);
            __builtin_amdgcn_global_load_lds(
                (const __attribute__((address_space(1))) void*)
                    (BT + (size_t)(bn + srow + j * 128) * QK_K + k0 + scol),
                (__attribute__((address_space(3))) void*)(&lds[rr][1][w * 512 + j * 4096]),
                16, 0, 0);
        }
    };

    stage(0); stage(1); stage(2);        // 12 loads in flight

#pragma unroll 1
    for (int T = 0; T < QK_NT; ++T) {
        if (T <= QK_NT - 3)      { asm volatile("s_waitcnt vmcnt(8)" ::: "memory"); }
        else if (T == QK_NT - 2) { asm volatile("s_waitcnt vmcnt(4)" ::: "memory"); }
        else                     { asm volatile("s_waitcnt vmcnt(0)" ::: "memory"); }
        __builtin_amdgcn_s_barrier();    // publish tile T; reads of ring (T-1)&3 done
        if (T <= QK_NT - 4) stage(T + 3);

        const int rr = T & 3;
        const unsigned short* Ald = &lds[rr][0][0];
        const unsigned short* Bld = &lds[rr][1][0];
        bf16x8 af[8], bfr[4];
#pragma unroll
        for (int mf = 0; mf < 8; ++mf)
            af[mf] = *(const bf16x8*)(Ald + (wm2 * 128 + mf * 16 + l15) * 32 + lg * 8);
#pragma unroll
        for (int nf = 0; nf < 4; ++nf)
            bfr[nf] = *(const bf16x8*)(Bld + (wn4 * 64 + nf * 16 + l15) * 32 + lg * 8);

        __builtin_amdgcn_s_setprio(1);
#pragma unroll
        for (int mf = 0; mf < 8; ++mf)
#pragma unroll
            for (int nf = 0; nf < 4; ++nf)
                acc[mf][nf] = __builtin_amdgcn_mfma_f32_16x16x32_bf16(af[mf], bfr[nf], acc[mf][nf], 0, 0, 0);
        __builtin_amdgcn_s_setprio(0);
    }

    // epilogue: bias + scatter Q (pre-scaled) / K bf16 [B,H,T,64], V -> Vt [B,H,64,T]
#pragma unroll
    for (int mf = 0; mf < 8; ++mf) {
#pragma unroll
        for (int nf = 0; nf < 4; ++nf) {
            int col = bn + wn4 * 64 + nf * 16 + l15;
            float bval = bias[col];
            int row0 = bm + wm2 * 128 + mf * 16 + lg * 4;
            float vals[4];
#pragma unroll
            for (int r = 0; r < 4; r++) vals[r] = acc[mf][nf][r] + bval;
            int b = row0 >> 11, t0 = row0 & 2047;
            int which = col >> 10;
            int h = (col & 1023) >> 6, d = col & 63;
            if (which == 2) {
                unsigned short pk[4];
#pragma unroll
                for (int r = 0; r < 4; r++) pk[r] = f2bf(vals[r]);
                *(unsigned long long*)(&Vt[((size_t)(b * H_ + h) * HD_ + d) * T_ + t0]) =
                    *(const unsigned long long*)pk;
            } else {
                unsigned short* dst = which ? Kb : Qb;
                float sc_ = which ? 1.0f : SCALE_LOG2E;
#pragma unroll
                for (int r = 0; r < 4; r++)
                    dst[((size_t)(b * H_ + h) * T_ + t0 + r) * HD_ + d] = f2bf(vals[r] * sc_);
            }
        }
    }
}

// ---------------- proj GEMM: m97 structure, 128^2 tile ----------------
__global__ __launch_bounds__(256) void k_proj(
    const unsigned short* __restrict__ A, const unsigned short* __restrict__ BT,
    const float* __restrict__ bias, float* __restrict__ out, int M, int N, int K)
{
    __shared__ unsigned short As[128][32];
    __shared__ unsigned short Bs[128][32];
    const int tid = threadIdx.x;
    const int lane = tid & 63;
    const int wv = tid >> 6;
    const int wm = wv >> 1, wn = wv & 1;
    const int l15 = lane & 15, lg = lane >> 4;

    const int nwg = gridDim.x * gridDim.y;
    const int orig = blockIdx.y * gridDim.x + blockIdx.x;
    const int wg = (orig & 7) * (nwg >> 3) + (orig >> 3);
    const int bm = (wg / gridDim.x) * 128, bn = (wg % gridDim.x) * 128;

    f32x4 acc[4][4];
#pragma unroll
    for (int m = 0; m < 4; m++)
#pragma unroll
        for (int n = 0; n < 4; n++) acc[m][n] = (f32x4){0.f, 0.f, 0.f, 0.f};

    const int rl = lane >> 2;
    const int cl = (lane & 3) * 8;

    for (int k0 = 0; k0 < K; k0 += 32) {
#pragma unroll
        for (int i = 0; i < 2; i++) {
            int c = wv + i * 4;
            __builtin_amdgcn_global_load_lds(
                (const __attribute__((address_space(1))) void*)
                    (&A[(size_t)(bm + c * 16 + rl) * K + k0 + cl]),
                (__attribute__((address_space(3))) void*)(&As[c * 16][0]), 16, 0, 0);
            __builtin_amdgcn_global_load_lds(
                (const __attribute__((address_space(1))) void*)
                    (&BT[(size_t)(bn + c * 16 + rl) * K + k0 + cl]),
                (__attribute__((address_space(3))) void*)(&Bs[c * 16][0]), 16, 0, 0);
        }
        __syncthreads();
        bf16x8 af[4], bfr[4];
#pragma unroll
        for (int m = 0; m < 4; m++) af[m]  = *(const bf16x8*)(&As[wm * 64 + m * 16 + l15][lg * 8]);
#pragma unroll
        for (int n = 0; n < 4; n++) bfr[n] = *(const bf16x8*)(&Bs[wn * 64 + n * 16 + l15][lg * 8]);
        __builtin_amdgcn_s_setprio(1);
#pragma unroll
        for (int m = 0; m < 4; m++)
#pragma unroll
            for (int n = 0; n < 4; n++)
                acc[m][n] = __builtin_amdgcn_mfma_f32_16x16x32_bf16(af[m], bfr[n], acc[m][n], 0, 0, 0);
        __builtin_amdgcn_s_setprio(0);
        __syncthreads();
    }

#pragma unroll
    for (int m = 0; m < 4; m++) {
#pragma unroll
        for (int n = 0; n < 4; n++) {
            int col = bn + wn * 64 + n * 16 + l15;
            float bval = bias[col];
            int row0 = bm + wm * 64 + m * 16 + lg * 4;
#pragma unroll
            for (int r = 0; r < 4; r++) out[(size_t)(row0 + r) * N + col] = acc[m][n][r] + bval;
        }
    }
}

// ---------------- Flash attention (causal): r10 inner loop, 1024-block grid ----------
// Q,K: [B*H, T, 64] (Q pre-scaled).  Vt: [B*H, 64, T].
// 1024 blocks (16 q-tiles x 64 heads), longest-first: t = 15-(j>>6), bh = j&63.
// 128 q-rows per block (16/wave x 8 waves). launch_bounds(512,4): VGPR 48 (no spill,
// r12's bug was (512,8) -> 32 VGPR -> 162GB scratch). Resources allow 4 blocks/CU;
// the 1024-block grid (vs r10's 512) lets the scheduler actually reach it.
__global__ __launch_bounds__(512, 4) void k_attn(
    const unsigned short* __restrict__ Qb, const unsigned short* __restrict__ Kb,
    const unsigned short* __restrict__ Vt, unsigned short* __restrict__ att)
{
    __shared__ unsigned short Ks[2][64][64];   // [buf][key][d], chunk16 ^= key&7
    __shared__ unsigned short Vs[2][64][64];   // [buf][d][newcol], chunk16 ^= d&7

    const int tid = threadIdx.x, lane = tid & 63, w = tid >> 6;   // w 0..7
    const int l15 = lane & 15, lg = lane >> 4;
    const int swq = l15 & 7;
    const int j = blockIdx.x;
    const int bh = j & 63;
    const int b = bh >> 4, h = bh & 15;
    const size_t kqbase = (size_t)bh * T_ * HD_;
    const size_t vtbase = (size_t)bh * HD_ * T_;

    const int r0 = tid >> 3;            // 0..63 staging row (one shot, 512 threads)
    const int mm = tid & 7;             // staging col chunk
    const int c8 = mm * 8;
    const int kch = mm;                               // K chunk (pre-swizzle)
    const int vch = 4 * (mm & 1) + (mm >> 2);         // V chunk half0 (pre-swizzle)
    const int voff = ((mm >> 1) & 1) * 4;             // shorts within chunk
    const int swr = r0 & 7;

    const int t = 15 - (j >> 6);            // longest-first 128-row q-tile
    const int qb = t * 128;
    const int qrow = qb + w * 16 + l15;     // this lane's q-row
    const int dtile = 2 * t + (w >> 2);     // wave-uniform diagonal tile
    const int ktlast = 2 * t + 1;           // block stages tiles 0..ktlast

    bf16x8 qf[2];
#pragma unroll
    for (int s = 0; s < 2; s++)
        qf[s] = *(const bf16x8*)(Qb + kqbase + (size_t)qrow * HD_ + s * 32 + lg * 8);

    f32x4 o[4];                   // o[cd][r] = O^T[d=cd*16+lg*4+r][q=l15]
    float m_run = -1e30f, l_run = 0.f;
#pragma unroll
    for (int c = 0; c < 4; c++) o[c] = (f32x4){0.f, 0.f, 0.f, 0.f};

    // prefetch tile 0
    int4v kreg, vreg;
    kreg = *(const int4v*)(Kb + kqbase + (size_t)r0 * HD_ + c8);
    vreg = *(const int4v*)(Vt + vtbase + (size_t)r0 * T_ + c8);

#pragma unroll 1
    for (int kt = 0; kt <= ktlast; ++kt) {
        const int bufi = kt & 1;
        *(int4v*)(&Ks[bufi][r0][(kch ^ swr) * 8]) = kreg;
        {
            unsigned long long vlo = ((const unsigned long long*)&vreg)[0];
            unsigned long long vhi = ((const unsigned long long*)&vreg)[1];
            *(unsigned long long*)(&Vs[bufi][r0][((vch       ^ swr) * 8) + voff]) = vlo;
            *(unsigned long long*)(&Vs[bufi][r0][(((vch + 2) ^ swr) * 8) + voff]) = vhi;
        }
        if (kt < ktlast) {                  // issue next tile's loads early (T14)
            int nk = (kt + 1) * 64;
            kreg = *(const int4v*)(Kb + kqbase + (size_t)(nk + r0) * HD_ + c8);
            vreg = *(const int4v*)(Vt + vtbase + (size_t)r0 * T_ + nk + c8);
        }
        __syncthreads();                    // single barrier per tile

        if (kt <= dtile) {
            // S^T = K Q^T : sv[c][r] = S[key=kt*64+c*16+lg*4+r][q=l15]
            float sv[4][4];
            const bool diag = (kt == dtile);
            __builtin_amdgcn_s_setprio(1);
#pragma unroll
            for (int c = 0; c < 4; c++) {
                bf16x8 kf0 = *(const bf16x8*)(&Ks[bufi][c * 16 + l15][(lg       ^ swq) * 8]);
                bf16x8 kf1 = *(const bf16x8*)(&Ks[bufi][c * 16 + l15][((4 + lg) ^ swq) * 8]);
                f32x4 s4 = (f32x4){0.f, 0.f, 0.f, 0.f};
                s4 = __builtin_amdgcn_mfma_f32_16x16x32_bf16(kf0, qf[0], s4, 0, 0, 0);
                s4 = __builtin_amdgcn_mfma_f32_16x16x32_bf16(kf1, qf[1], s4, 0, 0, 0);
                if (diag) {
                    int key0 = kt * 64 + c * 16 + lg * 4;
#pragma unroll
                    for (int r = 0; r < 4; r++)
                        sv[c][r] = (key0 + r > qrow) ? -1e30f : s4[r];
                } else {
#pragma unroll
                    for (int r = 0; r < 4; r++) sv[c][r] = s4[r];
                }
            }
            __builtin_amdgcn_s_setprio(0);

            // row max (whole q-row lane-local across 4 lane-group copies)
            float tm = fmaxf(fmaxf(fmaxf(sv[0][0], sv[0][1]), fmaxf(sv[0][2], sv[0][3])),
                             fmaxf(fmaxf(sv[1][0], sv[1][1]), fmaxf(sv[1][2], sv[1][3])));
            tm = fmaxf(tm, fmaxf(fmaxf(fmaxf(sv[2][0], sv[2][1]), fmaxf(sv[2][2], sv[2][3])),
                                 fmaxf(fmaxf(sv[3][0], sv[3][1]), fmaxf(sv[3][2], sv[3][3]))));
            tm = fmaxf(tm, __shfl_xor(tm, 16));
            tm = fmaxf(tm, __shfl_xor(tm, 32));

            // defer-max (T13): rescale only when a row's max grew past THR=8
            if (__any(tm - m_run > 8.f)) {
                float mn = fmaxf(m_run, tm);
                float alpha = exp2f(m_run - mn);
                m_run = mn;
                l_run *= alpha;
#pragma unroll
                for (int cd = 0; cd < 4; cd++)
#pragma unroll
                    for (int r = 0; r < 4; r++) o[cd][r] *= alpha;
            }

            // P in registers, packed per the kappa slot order (no LDS, no shuffles)
            float ps = 0.f;
            bf16x8 pf0, pf1;
#pragma unroll
            for (int c = 0; c < 2; c++)
#pragma unroll
                for (int r = 0; r < 4; r++) {
                    float pv0 = exp2f(sv[c][r] - m_run);
                    float pv1 = exp2f(sv[c + 2][r] - m_run);
                    ps += pv0 + pv1;
                    pf0[c * 4 + r] = (short)f2bf(pv0);
                    pf1[c * 4 + r] = (short)f2bf(pv1);
                }
            l_run += ps;

            // O^T += V~ P~ with matching slot->key map on both operands
            __builtin_amdgcn_s_setprio(1);
#pragma unroll
            for (int cd = 0; cd < 4; cd++) {
                bf16x8 vf0 = *(const bf16x8*)(&Vs[bufi][cd * 16 + l15][((2 * lg)     ^ swq) * 8]);
                bf16x8 vf1 = *(const bf16x8*)(&Vs[bufi][cd * 16 + l15][((2 * lg + 1) ^ swq) * 8]);
                o[cd] = __builtin_amdgcn_mfma_f32_16x16x32_bf16(vf0, pf0, o[cd], 0, 0, 0);
                o[cd] = __builtin_amdgcn_mfma_f32_16x16x32_bf16(vf1, pf1, o[cd], 0, 0, 0);
            }
            __builtin_amdgcn_s_setprio(0);
        }
    }

    // epilogue: cross-lane l reduce, normalize, store packed
    float ls = l_run;
    ls += __shfl_xor(ls, 16);
    ls += __shfl_xor(ls, 32);
    float inv = 1.0f / ls;
    const size_t rowbase = ((size_t)(b * T_ + qrow)) * C_ + h * 64;
#pragma unroll
    for (int cd = 0; cd < 4; cd++) {
        unsigned short ok[4];
#pragma unroll
        for (int r = 0; r < 4; r++) ok[r] = f2bf(o[cd][r] * inv);
        *(unsigned long long*)(&att[rowbase + cd * 16 + lg * 4]) =
            *(const unsigned long long*)ok;
    }
}

extern "C" void kernel_launch(void* const* d_in, const int* in_sizes, int n_in,
                              void* d_out, int out_size, void* d_ws, size_t ws_size,
                              hipStream_t stream)
{
    const float* x      = (const float*)d_in[0];
    const float* W_qkv  = (const float*)d_in[1];
    const float* b_qkv  = (const float*)d_in[2];
    const float* W_proj = (const float*)d_in[3];
    const float* b_proj = (const float*)d_in[4];
    float* out = (float*)d_out;

    char* p = (char*)d_ws;
    unsigned short* xbf    = (unsigned short*)p; p += (size_t)8192 * 1024 * 2;  // reused as att out
    unsigned short* wqkvT  = (unsigned short*)p; p += (size_t)3072 * 1024 * 2;
    unsigned short* wprojT = (unsigned short*)p; p += (size_t)1024 * 1024 * 2;
    unsigned short* Qb     = (unsigned short*)p; p += (size_t)8192 * 1024 * 2;
    unsigned short* Kb     = (unsigned short*)p; p += (size_t)8192 * 1024 * 2;
    unsigned short* Vt     = (unsigned short*)p; p += (size_t)8192 * 1024 * 2;  // [B*H, 64, T]

    k_conv<<<8192, 256, 0, stream>>>(x, xbf, 8192 * 1024);
    k_transp<<<dim3(96, 32), 256, 0, stream>>>(W_qkv, wqkvT, 1024, 3072);
    k_transp<<<dim3(32, 32), 256, 0, stream>>>(W_proj, wprojT, 1024, 1024);
    k_qkv<<<384, 512, 0, stream>>>(xbf, wqkvT, b_qkv, Qb, Kb, Vt);
    k_attn<<<1024, 512, 0, stream>>>(Qb, Kb, Vt, xbf);
    k_proj<<<dim3(8, 64), 256, 0, stream>>>(xbf, wprojT, b_proj, out, 8192, 1024, 1024);
}